// Round 8
// baseline (178.536 us; speedup 1.0000x reference)
//
#include <hip/hip_runtime.h>

#define R_    512
#define K_    17
#define HIN   56
#define WIN   56
#define OUTS  96
#define NMAP  (R_ * K_)
#define NT    192
#define RST   98            // tmp row stride in v2f
#define MAPSZ (HIN * WIN)   // 3136 floats
#define PAIRS 4
#define NBLK  (NMAP / (2 * PAIRS))   // 1088 blocks, 4 pairs each

typedef float v2f __attribute__((ext_vector_type(2)));

// Barrier that drains ONLY lgkmcnt (LDS) — leaves global prefetch loads in flight.
// 0xc07f = vmcnt 63 (unconstrained), expcnt 7, lgkmcnt 0.
__device__ __forceinline__ void bar_lds() {
    asm volatile("" ::: "memory");
    __builtin_amdgcn_s_waitcnt(0xc07f);
    __builtin_amdgcn_s_barrier();
    asm volatile("" ::: "memory");
}

constexpr float cubic_c(float xin) {
    float x = xin < 0.0f ? -xin : xin;
    const float A = -0.75f;
    if (x <= 1.0f) return ((A + 2.0f) * x - (A + 3.0f)) * x * x + 1.0f;
    if (x < 2.0f)  return A * (((x - 5.0f) * x + 8.0f) * x - 4.0f);
    return 0.0f;
}

// X-pass: folded effective weights on contiguous window [s, s+3] (border clamp folded).
struct XTabT {
    float w[OUTS][4];
    int   s[OUTS];
    constexpr XTabT() : w{}, s{} {
        for (int o = 0; o < OUTS; ++o) {
            float src = ((float)o + 0.5f) * (56.0f / 96.0f) - 0.5f;
            int base = (int)src;
            if ((float)base > src) --base;
            int st = base - 1;
            if (st < 0) st = 0;
            if (st > HIN - 4) st = HIN - 4;
            s[o] = st;
            for (int q = 0; q < 4; ++q) {
                int tap = base - 1 + q;
                float wt = cubic_c(src - (float)tap);
                int p = tap < 0 ? 0 : (tap > HIN - 1 ? HIN - 1 : tap);
                w[o][p - st] += wt;
            }
        }
    }
};
constexpr XTabT XT;

// Y-pass: period-12 raw weights + relative tap start (tap0 logical row = 7*(h/12)+d[h%12]).
// Border via replicated pad rows in tmp (validated rounds 5/6: absmax 0.0).
struct YTabT {
    float w[12][4];
    int   d[12];
    constexpr YTabT() : w{}, d{} {
        for (int ph = 0; ph < 12; ++ph) {
            float src = ((float)ph + 0.5f) * (56.0f / 96.0f) - 0.5f;
            int base = (int)src;
            if ((float)base > src) --base;
            d[ph] = base - 1;
            for (int q = 0; q < 4; ++q)
                w[ph][q] = cubic_c(src - (float)(base - 1 + q));
        }
    }
};
constexpr YTabT YT;

// x-pass FMAs for col group G (cols 32G..32G+31) from rr = floats 16G..16G+23 (packed maps).
template<int G>
__device__ __forceinline__ void p1fma(const v2f (&rr)[24], v2f* __restrict__ dst) {
#pragma unroll
    for (int i = 0; i < 16; ++i) {
        const int o0 = 32 * G + 2 * i, o1 = o0 + 1;
        const int s0 = XT.s[o0] - 16 * G, s1 = XT.s[o1] - 16 * G;
        v2f a0 = rr[s0] * (v2f){XT.w[o0][0], XT.w[o0][0]};
        a0 = __builtin_elementwise_fma((v2f){XT.w[o0][1], XT.w[o0][1]}, rr[s0 + 1], a0);
        a0 = __builtin_elementwise_fma((v2f){XT.w[o0][2], XT.w[o0][2]}, rr[s0 + 2], a0);
        a0 = __builtin_elementwise_fma((v2f){XT.w[o0][3], XT.w[o0][3]}, rr[s0 + 3], a0);
        v2f a1 = rr[s1] * (v2f){XT.w[o1][0], XT.w[o1][0]};
        a1 = __builtin_elementwise_fma((v2f){XT.w[o1][1], XT.w[o1][1]}, rr[s1 + 1], a1);
        a1 = __builtin_elementwise_fma((v2f){XT.w[o1][2], XT.w[o1][2]}, rr[s1 + 2], a1);
        a1 = __builtin_elementwise_fma((v2f){XT.w[o1][3], XT.w[o1][3]}, rr[s1 + 3], a1);
        *(float4*)(dst + 2 * i) = (float4){a0.x, a0.y, a1.x, a1.y};   // ds_write_b128
    }
}

// y-value: bit-identical chain shared by max-pass and rescan.
__device__ __forceinline__ v2f yv(const v2f* __restrict__ c, int hh) {
    const int ph = hh % 12, b = hh / 12;
    const int i0 = 7 * b + YT.d[ph] + 2;            // in [0,28]; +3 <= 31
    v2f acc = c[i0] * (v2f){YT.w[ph][0], YT.w[ph][0]};
    acc = __builtin_elementwise_fma((v2f){YT.w[ph][1], YT.w[ph][1]}, c[i0 + 1], acc);
    acc = __builtin_elementwise_fma((v2f){YT.w[ph][2], YT.w[ph][2]}, c[i0 + 2], acc);
    acc = __builtin_elementwise_fma((v2f){YT.w[ph][3], YT.w[ph][3]}, c[i0 + 3], acc);
    return acc;
}

__global__ __launch_bounds__(NT, 2)
void _Keypointer_kernel(const float* __restrict__ masks,
                        const float* __restrict__ boxes,
                        float* __restrict__ out) {
    __shared__ __align__(16) v2f tmp[60 * RST];     // 47040 B -> 3 blocks/CU
    __shared__ v2f wmax[3];
    __shared__ int candp[2];

    const int t = threadIdx.x;
    const int g = t >> 6;                           // col group (wave-uniform)
    const int w = t & 63;
    const int srcrow = min(max(w - 2, 0), HIN - 1); // zero-divergence pads
    const int phys   = min(w, 59);
    const int half   = (t >= 96) ? 1 : 0;
    const int col    = t - 96 * half;
    const v2f* cb    = tmp + 28 * half * RST + col;
    v2f* dst         = tmp + phys * RST + 32 * g;

    const int pair0 = PAIRS * blockIdx.x;
    const float4* gp = (const float4*)(masks + (size_t)(2 * pair0) * MAPSZ
                                       + srcrow * WIN) + 4 * g;  // 24-float window

    if (t < 2) candp[t] = 0x7fffffff;

    // prologue prefetch: 6 float4 per map (floats 16g..16g+23)
    float4 pa[6], pb[6];
#pragma unroll
    for (int i = 0; i < 6; ++i) { pa[i] = gp[i]; pb[i] = gp[MAPSZ / 4 + i]; }

#pragma unroll 1
    for (int it = 0; it < PAIRS; ++it) {
        // consume prefetch into packed v2f (map0, map1)
        v2f rr[24];
#pragma unroll
        for (int i = 0; i < 6; ++i) {
            rr[4 * i + 0] = (v2f){pa[i].x, pb[i].x};
            rr[4 * i + 1] = (v2f){pa[i].y, pb[i].y};
            rr[4 * i + 2] = (v2f){pa[i].z, pb[i].z};
            rr[4 * i + 3] = (v2f){pa[i].w, pb[i].w};
        }
        // issue next pair's loads NOW — they stay in flight across the lgkm-only barriers
        if (it + 1 < PAIRS) {
            gp += 2 * (MAPSZ / 4);
#pragma unroll
            for (int i = 0; i < 6; ++i) { pa[i] = gp[i]; pb[i] = gp[MAPSZ / 4 + i]; }
        }
        // x-pass -> tmp
        if      (g == 0) p1fma<0>(rr, dst);
        else if (g == 1) p1fma<1>(rr, dst);
        else             p1fma<2>(rr, dst);
        bar_lds();                                  // tmp ready (lgkm only)

        // y-pass + max (both maps packed)
        v2f c[32];
#pragma unroll
        for (int i = 0; i < 32; ++i) c[i] = cb[i * RST];
        v2f vm = {-INFINITY, -INFINITY};
#pragma unroll
        for (int hh = 0; hh < 48; ++hh)
            vm = __builtin_elementwise_max(vm, yv(c, hh));

        float m0 = vm.x, m1 = vm.y;
#pragma unroll
        for (int off = 32; off > 0; off >>= 1) {
            m0 = fmaxf(m0, __shfl_down(m0, off, 64));
            m1 = fmaxf(m1, __shfl_down(m1, off, 64));
        }
        if (w == 0) wmax[g] = (v2f){m0, m1};
        bar_lds();                                  // wmax ready

        const float M0 = fmaxf(fmaxf(wmax[0].x, wmax[1].x), wmax[2].x);
        const float M1 = fmaxf(fmaxf(wmax[0].y, wmax[1].y), wmax[2].y);

        // sparse rescan (bit-identical recompute) -> first-occurrence argmax
        if (vm.x == M0 || vm.y == M1) {
            int c0 = 0x7fffffff, c1 = 0x7fffffff;
#pragma unroll
            for (int hh = 0; hh < 48; ++hh) {
                v2f a = yv(c, hh);
                int fp = (48 * half + hh) * OUTS + col;
                if (a.x == M0) c0 = min(c0, fp);
                if (a.y == M1) c1 = min(c1, fp);
            }
            if (c0 != 0x7fffffff) atomicMin(&candp[0], c0);
            if (c1 != 0x7fffffff) atomicMin(&candp[1], c1);
        }
        bar_lds();                                  // candp final; tmp consumable

        if (t < 2) {
            const int map = 2 * (pair0 + it) + t;
            const float M = t ? M1 : M0;
            const int bp = candp[t];
            candp[t] = 0x7fffffff;                  // re-arm own slot for next iter
            const int r = map / K_, k = map - r * K_;
            const int y = bp / OUTS, x = bp - y * OUTS;
            const float b0f = boxes[r * 4 + 0], b1f = boxes[r * 4 + 1];
            const float b2f = boxes[r * 4 + 2], b3f = boxes[r * 4 + 3];
            const float corr0 = fmaxf(b2f - b0f, 1.0f) / (float)OUTS;
            const float corr1 = fmaxf(b3f - b1f, 1.0f) / (float)OUTS;
            out[(r * 3 + 0) * K_ + k] = ((float)y + 0.5f) * corr0 + b0f;
            out[(r * 3 + 1) * K_ + k] = ((float)x + 0.5f) * corr1 + b1f;
            out[(r * 3 + 2) * K_ + k] = 1.0f;
            out[R_ * 3 * K_ + r * K_ + k] = M;
        }
    }
}

extern "C" void kernel_launch(void* const* d_in, const int* in_sizes, int n_in,
                              void* d_out, int out_size, void* d_ws, size_t ws_size,
                              hipStream_t stream) {
    const float* masks = (const float*)d_in[0];
    const float* boxes = (const float*)d_in[1];
    float* out = (float*)d_out;
    _Keypointer_kernel<<<NBLK, NT, 0, stream>>>(masks, boxes, out);
}